// Round 3
// baseline (382.670 us; speedup 1.0000x reference)
//
#include <hip/hip_runtime.h>
#include <hip/hip_bf16.h>
#include <stdint.h>

// Problem sizes (compile-time)
static constexpr int BATCH = 32768;
static constexpr int DIN   = 512;
static constexpr int DHID  = 1024;
static constexpr int DOUT  = 2048;

typedef __bf16 bf16x8 __attribute__((ext_vector_type(8)));
typedef float  f32x4  __attribute__((ext_vector_type(4)));

// fp32 -> bf16 round-to-nearest-even
__device__ __forceinline__ unsigned short f2bf(float f) {
    unsigned int u = __float_as_uint(f);
    u += 0x7FFFu + ((u >> 16) & 1u);
    return (unsigned short)(u >> 16);
}

// async global->LDS, 16B per lane. LDS dest = WAVE-uniform base + 16*(lane&63).
__device__ __forceinline__ void gload_lds16(const void* g, void* l) {
    __builtin_amdgcn_global_load_lds((__attribute__((address_space(1))) void*)g,
                                     (__attribute__((address_space(3))) void*)l,
                                     16, 0, 0);
}

// ===========================================================================
// scores = x @ W^T + b' (algebraic fusion; absmax 0.03125 measured)
// r17: persistent gemmS, N-WALK variant. r16's M-walk spilled (WRITE 462MB,
// VGPR pinned at 128-arch cap): full epilogue in-loop exceeded the 256-reg
// budget (512-thr block => 2 waves/SIMD => cap 256; r15 used ~240).
// Fix: block keeps its 256 output ROWS fixed and walks 4 N-tiles; per-tile
// epilogue becomes a 32-reg running-max fold (no stores, no shuffles in
// loop). Bias staged to LDS (132KB block), bv reloaded per tile via
// ds_read (lgkm — never touches the counted vmcnt stream). Stores happen
// once, after the drain. Phase schedule = r16 mirror (A stable, B walks),
// which hardware-validated correct in r16.
// ===========================================================================

// ---------------------------------------------------------------------------
// prep: one dispatch, region-decoded by blockIdx.x (unchanged)
// ---------------------------------------------------------------------------
__global__ __launch_bounds__(256) void prep_kernel(
    const float* __restrict__ w1, const float4* __restrict__ w2f,
    const float4* __restrict__ xf, const float* __restrict__ b1,
    const float* __restrict__ b2,
    unsigned short* __restrict__ w1t, ushort4* __restrict__ w2b,
    ushort4* __restrict__ xb, float* __restrict__ bp) {
    const int blk = blockIdx.x;
    const int t   = threadIdx.x;
    if (blk < 512) {
        __shared__ float tile[32][33];
        const int tileI = blk & 15;
        const int tileH = blk >> 4;
        const int iBase = tileI * 32, hBase = tileH * 32;
        const int col = t & 31, rowq = t >> 5;
#pragma unroll
        for (int p = 0; p < 4; ++p) {
            const int row = p * 8 + rowq;
            tile[row][col] = w1[(size_t)(hBase + row) * DIN + iBase + col];
        }
        __syncthreads();
#pragma unroll
        for (int p = 0; p < 4; ++p) {
            const int row = p * 8 + rowq;
            w1t[(size_t)(iBase + row) * DHID + hBase + col] = f2bf(tile[col][row]);
        }
    } else if (blk < 2560) {
        __shared__ float wsum[4];
        const int o = blk - 512;
        const size_t g = (size_t)o * 256 + t;
        float4 v = w2f[g];
        ushort4 ob;
        ob.x = f2bf(v.x); ob.y = f2bf(v.y); ob.z = f2bf(v.z); ob.w = f2bf(v.w);
        w2b[g] = ob;
        float4 bv = ((const float4*)b1)[t];
        float s = v.x * bv.x + v.y * bv.y + v.z * bv.z + v.w * bv.w;
#pragma unroll
        for (int off = 1; off < 64; off <<= 1) s += __shfl_xor(s, off);
        if ((t & 63) == 0) wsum[t >> 6] = s;
        __syncthreads();
        if (t == 0) bp[o] = wsum[0] + wsum[1] + wsum[2] + wsum[3] + b2[o];
    } else {
        const size_t g = (size_t)(blk - 2560) * 256 + t;
        float4 v = xf[g];
        ushort4 o;
        o.x = f2bf(v.x); o.y = f2bf(v.y); o.z = f2bf(v.z); o.w = f2bf(v.w);
        xb[g] = o;
    }
}

// ---------------------------------------------------------------------------
// gemmW: W[o,i] = sum_h w2b[o,h] * w1t[i,h]. (unchanged)
// ---------------------------------------------------------------------------
__global__ __launch_bounds__(256) void gemmW_kernel(
    const unsigned short* __restrict__ A,
    const unsigned short* __restrict__ Bw,
    unsigned short* __restrict__ W) {
    constexpr int K = DHID;
    __shared__ __align__(16) unsigned short sA[64 * 128];
    __shared__ __align__(16) unsigned short sB[64 * 128];

    const int tid  = threadIdx.x;
    const int lane = tid & 63;
    const int wid  = tid >> 6;
    const int wr = wid >> 1, wc = wid & 1;
    const int r = lane & 15, q = lane >> 4;
    const int blockN = blockIdx.x * 64;
    const int blockM = blockIdx.y * 64;

    const int chKey = (tid & 15) ^ ((tid >> 4) & 15);
    const size_t aBase = (size_t)(blockM + (tid >> 4)) * K + chKey * 8;
    const size_t bBase = (size_t)(blockN + (tid >> 4)) * K + chKey * 8;

    f32x4 acc[2][2];
#pragma unroll
    for (int mt = 0; mt < 2; ++mt)
#pragma unroll
        for (int nt = 0; nt < 2; ++nt) { f32x4 z = {0.f, 0.f, 0.f, 0.f}; acc[mt][nt] = z; }

    for (int k0 = 0; k0 < K; k0 += 128) {
#pragma unroll
        for (int j = 0; j < 4; ++j) {
            gload_lds16(A  + aBase + (size_t)j * 16 * K + k0, sA + j * 2048 + wid * 512);
            gload_lds16(Bw + bBase + (size_t)j * 16 * K + k0, sB + j * 2048 + wid * 512);
        }
        __syncthreads();
#pragma unroll
        for (int ks = 0; ks < 4; ++ks) {
            const int ch = ((ks << 2) + q) ^ r;
            bf16x8 af[2], bf[2];
#pragma unroll
            for (int mt = 0; mt < 2; ++mt) af[mt] = *(const bf16x8*)&sA[(wr * 32 + mt * 16 + r) * 128 + ch * 8];
#pragma unroll
            for (int nt = 0; nt < 2; ++nt) bf[nt] = *(const bf16x8*)&sB[(wc * 32 + nt * 16 + r) * 128 + ch * 8];
#pragma unroll
            for (int mt = 0; mt < 2; ++mt)
#pragma unroll
                for (int nt = 0; nt < 2; ++nt)
                    acc[mt][nt] = __builtin_amdgcn_mfma_f32_16x16x32_bf16(af[mt], bf[nt], acc[mt][nt], 0, 0, 0);
        }
        __syncthreads();
    }

#pragma unroll
    for (int mt = 0; mt < 2; ++mt) {
        const int row0 = blockM + wr * 32 + mt * 16 + q * 4;
#pragma unroll
        for (int nt = 0; nt < 2; ++nt) {
            const int col = blockN + wc * 32 + nt * 16 + r;
#pragma unroll
            for (int reg = 0; reg < 4; ++reg)
                W[(size_t)(row0 + reg) * DIN + col] = f2bf(acc[mt][nt][reg]);
        }
    }
}

// ---------------------------------------------------------------------------
// gemmS r17: persistent 256-block, N-walk, running-max fold.
// Block = fixed 256 rows (mIdx), walks 4 N-tiles (nGrp*1024 + t*256).
// LDS: A region [0,32K shorts) stable-op, B region [16K..) per buf as r15/r16;
// bias [65536..67584 shorts) = 4KB (4 tiles x 256 f32).
// ---------------------------------------------------------------------------
__global__ __launch_bounds__(512, 2) void gemmS_kernel(
    const unsigned short* __restrict__ A,   // xb bf16 [BATCH, DIN]
    const unsigned short* __restrict__ Bw,  // W bf16 [DOUT, DIN]
    const float* __restrict__ bp,           // b' [DOUT]
    float* __restrict__ partials) {         // [BATCH, 8]
    constexpr int K = DIN;                   // 512 -> 8 K-tiles per out-tile
    __shared__ __align__(16) unsigned short lds[67584];  // 132 KB (128 + 4 bias)

    const int tid  = threadIdx.x;            // 0..511
    const int lane = tid & 63;
    const int wid  = tid >> 6;               // 0..7
    const int wr   = wid >> 2;               // 0..1 (M)
    const int wc   = wid & 3;                // 0..3 (N)
    const int r    = lane & 15, q = lane >> 4;

    // 256 blocks = 8 xcd x 32. Block: mIdx = xcd*16 + (j>>1), nGrp = j&1.
    // XCD's 16 blocks per nGrp share the same 1MB B half -> L2-resident.
    const int b    = blockIdx.x;
    const int xcd  = b & 7;
    const int j    = b >> 3;                 // 0..31
    const int nGrp = j & 1;                  // 0..1
    const int mIdx = xcd * 16 + (j >> 1);    // 0..127
    const int blockM  = mIdx * 256;
    const int blockN0 = nGrp * 1024;         // tile t adds t*256

    // staging addresses (pre-swizzled global source)
    const int sRow = tid >> 2;               // 0..127 (j=1 adds 128)
    const int swz  = (tid & 3) ^ ((tid >> 3) & 3);
    const unsigned short* aSrc = A  + (size_t)(blockM  + sRow) * K + swz * 8;
    const unsigned short* bCur = Bw + (size_t)(blockN0 + sRow) * K + swz * 8;
    unsigned short* ldsW = lds + wid * 512;  // wave-uniform stage base
    float* biasLds = (float*)(lds + 65536);  // byte 131072, 1024 f32

#define STAGE(srcPtr, isB, buf, kh, kt) do {                                    \
    gload_lds16((srcPtr) + (kt) * 64 + (kh) * 32,                               \
                ldsW + (buf) * 32768 + (isB) * 16384 + (kh) * 8192);            \
    gload_lds16((srcPtr) + 128 * K + (kt) * 64 + (kh) * 32,                     \
                ldsW + (buf) * 32768 + (isB) * 16384 + (kh) * 8192 + 4096);     \
} while (0)

    // fragment read bases (swizzled chunk)
    const int rsw  = (r >> 1) & 3;
    const int fOff = (q ^ rsw) * 8;
    const unsigned short* ldsAf = lds + (wr * 128 + r) * 32 + fOff;
    const unsigned short* ldsBf = lds + 16384 + (wc * 64 + r) * 32 + fOff;

    f32x4 acc[8][4];
#pragma unroll
    for (int mt = 0; mt < 8; ++mt)
#pragma unroll
        for (int nt = 0; nt < 4; ++nt) { f32x4 z = {0.f, 0.f, 0.f, 0.f}; acc[mt][nt] = z; }
    float mx[8][4];
#pragma unroll
    for (int mt = 0; mt < 8; ++mt)
#pragma unroll
        for (int rg = 0; rg < 4; ++rg) mx[mt][rg] = -INFINITY;
    bf16x8 af[4], bfr[4];
    float bvc[4];

#define LDA(buf, ks, mg) do {                                                   \
    const unsigned short* p_ = ldsAf + (buf) * 32768 + (ks) * 8192 + (mg) * 2048; \
    af[0] = *(const bf16x8*)(p_);                                               \
    af[1] = *(const bf16x8*)(p_ + 512);                                         \
    af[2] = *(const bf16x8*)(p_ + 1024);                                        \
    af[3] = *(const bf16x8*)(p_ + 1536);                                        \
} while (0)
#define LDB(buf, ks) do {                                                       \
    const unsigned short* p_ = ldsBf + (buf) * 32768 + (ks) * 8192;             \
    bfr[0] = *(const bf16x8*)(p_);                                              \
    bfr[1] = *(const bf16x8*)(p_ + 512);                                        \
    bfr[2] = *(const bf16x8*)(p_ + 1024);                                       \
    bfr[3] = *(const bf16x8*)(p_ + 1536);                                       \
} while (0)
#define MM(mg) do {                                                             \
    __builtin_amdgcn_s_setprio(1);                                              \
    _Pragma("unroll") for (int m_ = 0; m_ < 4; ++m_)                            \
    _Pragma("unroll") for (int n_ = 0; n_ < 4; ++n_)                            \
        acc[(mg) * 4 + m_][n_] = __builtin_amdgcn_mfma_f32_16x16x32_bf16(       \
            af[m_], bfr[n_], acc[(mg) * 4 + m_][n_], 0, 0, 0);                  \
    __builtin_amdgcn_s_setprio(0);                                              \
} while (0)
#define BAR()   __builtin_amdgcn_s_barrier()
#define LGKM0() asm volatile("s_waitcnt lgkmcnt(0)" ::: "memory")
#define VMC(n)  asm volatile("s_waitcnt vmcnt(" #n ")" ::: "memory")

    // Running-max fold: mx = max(mx, max_nt(acc+bv)). 32 regs, no stores.
#define FOLD() do {                                                             \
    _Pragma("unroll") for (int mt_ = 0; mt_ < 8; ++mt_)                         \
    _Pragma("unroll") for (int rg_ = 0; rg_ < 4; ++rg_) {                       \
        float v_ = fmaxf(fmaxf(acc[mt_][0][rg_] + bvc[0],                       \
                               acc[mt_][1][rg_] + bvc[1]),                      \
                         fmaxf(acc[mt_][2][rg_] + bvc[2],                       \
                               acc[mt_][3][rg_] + bvc[3]));                     \
        mx[mt_][rg_] = fmaxf(mx[mt_][rg_], v_);                                 \
    }                                                                           \
} while (0)

#define ACC_ZERO() do {                                                         \
    _Pragma("unroll") for (int mt_ = 0; mt_ < 8; ++mt_)                         \
    _Pragma("unroll") for (int nt_ = 0; nt_ < 4; ++nt_) {                       \
        f32x4 z_ = {0.f, 0.f, 0.f, 0.f}; acc[mt_][nt_] = z_;                    \
    }                                                                           \
} while (0)

    // Bias -> LDS (4KB): 512 thr x 2 f32. Compiler inserts the vmcnt wait
    // before ds_write, so the loads never linger in the counted stream.
    {
        float2 bb = ((const float2*)(bp + blockN0))[tid];
        ((float2*)biasLds)[tid] = bb;
    }
    LGKM0();   // own ds_write done before barrier (visibility after BAR)

    // Prologue: slot0 (4 units) + slot1 (3 units); land slot0 (vmcnt 14->6).
    STAGE(bCur, 1, 0, 0, 0);
    STAGE(aSrc, 0, 0, 0, 0);
    STAGE(bCur, 1, 0, 1, 0);
    STAGE(aSrc, 0, 0, 1, 0);
    STAGE(bCur, 1, 1, 0, 1);
    STAGE(aSrc, 0, 1, 0, 1);
    STAGE(bCur, 1, 1, 1, 1);
    VMC(6);
    BAR();

    // bias for tile 0 (ds_read; covered by P1's LGKM0)
#pragma unroll
    for (int nt = 0; nt < 4; ++nt) bvc[nt] = biasLds[wc * 64 + nt * 16 + r];

#pragma unroll 1
    for (int t = 0; t < 4; ++t) {
        // 3 uniform iterations: slots 8t+2i2, 8t+2i2+1; stages stay in tile t.
#pragma unroll 1
        for (int i2 = 0; i2 < 3; ++i2) {
            const int k1 = 2 * i2 + 1, k2 = 2 * i2 + 2, k3 = 2 * i2 + 3;
            // P1
            LDA(0, 0, 0); LDB(0, 0); STAGE(aSrc, 0, 1, 1, k1);
            BAR(); LGKM0(); MM(0); BAR();
            // P2
            LDA(0, 0, 1); STAGE(bCur, 1, 0, 0, k2);
            BAR(); LGKM0(); MM(1); BAR();
            // P3
            LDA(0, 1, 0); LDB(0, 1); STAGE(aSrc, 0, 0, 0, k2);
            BAR(); LGKM0(); MM(0); BAR();
            // P4
            LDA(0, 1, 1); STAGE(bCur, 1, 0, 1, k2); VMC(6);
            BAR(); LGKM0(); MM(1); BAR();
            // P5
            LDA(1, 0, 0); LDB(1, 0); STAGE(aSrc, 0, 0, 1, k2);
            BAR(); LGKM0(); MM(0); BAR();
            // P6
            LDA(1, 0, 1); STAGE(bCur, 1, 1, 0, k3);
            BAR(); LGKM0(); MM(1); BAR();
            // P7
            LDA(1, 1, 0); LDB(1, 1); STAGE(aSrc, 0, 1, 0, k3);
            BAR(); LGKM0(); MM(0); BAR();
            // P8
            LDA(1, 1, 1); STAGE(bCur, 1, 1, 1, k3); VMC(6);
            BAR(); LGKM0(); MM(1); BAR();
        }
        if (t < 3) {
            // Boundary iteration: slots 8t+6, 8t+7; B rolls to tile t+1
            // (bNxt at kt=0/1), A (stable) wraps to kt=0/1.
            const unsigned short* bNxt = bCur + 256 * K;
            LDA(0, 0, 0); LDB(0, 0); STAGE(aSrc, 0, 1, 1, 7);
            BAR(); LGKM0(); MM(0); BAR();
            LDA(0, 0, 1); STAGE(bNxt, 1, 0, 0, 0);
            BAR(); LGKM0(); MM(1); BAR();
            LDA(0, 1, 0); LDB(0, 1); STAGE(aSrc, 0, 0, 0, 0);
            BAR(); LGKM0(); MM(0); BAR();
            LDA(0, 1, 1); STAGE(bNxt, 1, 0, 1, 0); VMC(6);
            BAR(); LGKM0(); MM(1); BAR();
            LDA(1, 0, 0); LDB(1, 0); STAGE(aSrc, 0, 0, 1, 0);
            BAR(); LGKM0(); MM(0); BAR();
            LDA(1, 0, 1); STAGE(bNxt, 1, 1, 0, 1);
            BAR(); LGKM0(); MM(1); BAR();
            LDA(1, 1, 0); LDB(1, 1); STAGE(aSrc, 0, 1, 0, 1);
            BAR(); LGKM0(); MM(0); BAR();
            LDA(1, 1, 1); STAGE(bNxt, 1, 1, 1, 1); VMC(6);
            BAR(); LGKM0(); MM(1); BAR();
            // Tile done: fold into running max; reload bias; advance B.
            FOLD();
            ACC_ZERO();
#pragma unroll
            for (int nt = 0; nt < 4; ++nt)
                bvc[nt] = biasLds[(t + 1) * 256 + wc * 64 + nt * 16 + r];
            bCur = bNxt;
        } else {
            // Drain iteration: slots 30, 31; only slot31's A-khi remains.
            LDA(0, 0, 0); LDB(0, 0); STAGE(aSrc, 0, 1, 1, 7);
            BAR(); LGKM0(); MM(0); BAR();
            LDA(0, 0, 1);
            BAR(); LGKM0(); MM(1); BAR();
            LDA(0, 1, 0); LDB(0, 1);
            BAR(); LGKM0(); MM(0); BAR();
            LDA(0, 1, 1); VMC(0);
            BAR(); LGKM0(); MM(1); BAR();
            LDA(1, 0, 0); LDB(1, 0);
            BAR(); LGKM0(); MM(0); BAR();
            LDA(1, 0, 1);
            BAR(); LGKM0(); MM(1); BAR();
            LDA(1, 1, 0); LDB(1, 1);
            BAR(); LGKM0(); MM(0); BAR();
            LDA(1, 1, 1);
            BAR(); LGKM0(); MM(1);
            FOLD();
        }
    }

#undef STAGE
#undef LDA
#undef LDB
#undef MM
#undef BAR
#undef LGKM0
#undef VMC
#undef FOLD
#undef ACC_ZERO

    // Final epilogue (once): 16-lane reduce of mx, store partials [BATCH,8].
#pragma unroll
    for (int mt = 0; mt < 8; ++mt) {
#pragma unroll
        for (int rg = 0; rg < 4; ++rg) {
            float v = mx[mt][rg];
#pragma unroll
            for (int off = 1; off < 16; off <<= 1)
                v = fmaxf(v, __shfl_xor(v, off));
            if (r == 0) {
                const int row = blockM + wr * 128 + mt * 16 + q * 4 + rg;
                partials[(size_t)row * 8 + nGrp * 4 + wc] = v;
            }
        }
    }
}

// ---------------------------------------------------------------------------
// reduce: 8 partials per row -> final max
// ---------------------------------------------------------------------------
__global__ __launch_bounds__(256) void reduce_kernel(
    const float4* __restrict__ partials, float* __restrict__ out) {
    const int row = blockIdx.x * blockDim.x + threadIdx.x;
    const float4* p = partials + (size_t)row * 2;
    float4 v0 = p[0], v1 = p[1];
    float m = fmaxf(fmaxf(fmaxf(v0.x, v0.y), fmaxf(v0.z, v0.w)),
                    fmaxf(fmaxf(v1.x, v1.y), fmaxf(v1.z, v1.w)));
    out[row] = m;
}

// ---------------------------------------------------------------------------
extern "C" void kernel_launch(void* const* d_in, const int* in_sizes, int n_in,
                              void* d_out, int out_size, void* d_ws, size_t ws_size,
                              hipStream_t stream) {
    const float* x   = (const float*)d_in[0];
    const float* l1w = (const float*)d_in[1];
    const float* l1b = (const float*)d_in[2];
    const float* w2  = (const float*)d_in[3];
    const float* b2  = (const float*)d_in[4];
    float* out = (float*)d_out;

    char* ws = (char*)d_ws;
    unsigned short* w1t = (unsigned short*)(ws);                 //  1 MB  w1^T bf16 [512,1024]
    unsigned short* w2b = (unsigned short*)(ws + 1048576);       //  4 MB  w2 bf16 [2048,1024]
    unsigned short* Wb  = (unsigned short*)(ws + 5242880);       //  2 MB  W bf16 [2048,512]
    float* bp           = (float*)(ws + 7340032);                //  8 KB  b' fp32 [2048]
    unsigned short* xb  = (unsigned short*)(ws + 7348224);       // 32 MB  x bf16 [32768,512]
    float* partials     = (float*)(ws + 40902656);               //  1 MB  [BATCH,8]

    // 1) fused pre-work: w1 transpose + w2 cvt(+bgemv) + x cvt
    prep_kernel<<<18944, 256, 0, stream>>>(
        l1w, (const float4*)w2, (const float4*)x, l1b, b2,
        w1t, (ushort4*)w2b, (ushort4*)xb, bp);

    // 2) W = w2b @ w1t^T  [2048, 512]
    gemmW_kernel<<<dim3(DIN / 64, DOUT / 64), 256, 0, stream>>>(w2b, w1t, Wb);

    // 3) scores = xb @ W^T + b', fused row-max (persistent N-walk, 256 blocks)
    gemmS_kernel<<<256, 512, 0, stream>>>(xb, Wb, bp, partials);

    // 4) final max over 8 partials per row
    reduce_kernel<<<BATCH / 256, 256, 0, stream>>>((const float4*)partials, out);
}

// Round 4
// 187.412 us; speedup vs baseline: 2.0419x; 2.0419x over previous
//
#include <hip/hip_runtime.h>
#include <hip/hip_bf16.h>
#include <stdint.h>

// Problem sizes (compile-time)
static constexpr int BATCH = 32768;
static constexpr int DIN   = 512;
static constexpr int DHID  = 1024;
static constexpr int DOUT  = 2048;

typedef __bf16 bf16x8 __attribute__((ext_vector_type(8)));
typedef float  f32x4  __attribute__((ext_vector_type(4)));

// fp32 -> bf16 round-to-nearest-even
__device__ __forceinline__ unsigned short f2bf(float f) {
    unsigned int u = __float_as_uint(f);
    u += 0x7FFFu + ((u >> 16) & 1u);
    return (unsigned short)(u >> 16);
}

// async global->LDS, 16B per lane. LDS dest = WAVE-uniform base + 16*(lane&63).
__device__ __forceinline__ void gload_lds16(const void* g, void* l) {
    __builtin_amdgcn_global_load_lds((__attribute__((address_space(1))) void*)g,
                                     (__attribute__((address_space(3))) void*)l,
                                     16, 0, 0);
}

// ===========================================================================
// scores = x @ W^T + b' (algebraic fusion; absmax 0.03125 measured)
// r18: persistent gemmS with SMALL accumulator. r16/r17 spilled (WRITE
// ~500MB, VGPR pinned at 128) because acc=128 AGPRs force a 128/128 unified
// split and the VGPR half can't hold in-loop epilogue state. Fix: BN=128,
// waves 4Mx2N -> acc[4][4]=64 AGPR, mx[4][4]=16; VGPR demand ~110 with a
// 192/64 split. N-walk running-max fold (no in-loop stores); one fill +
// one drain per kernel (64 K-tiles deep pipeline).
// Schedule: 4 phases / 2 K-tiles; phase = {4 LDA + 4 LDB ds_read_b128,
// 1 STAGE_A(2 loads)+1 STAGE_B(1 load), vmcnt(6), bar, lgkm0, 16 MFMA, bar}.
// Ledger (verified): steady outstanding 6->9->VMC(6) every phase; stage
// targets only units freed in the PREVIOUS phase (>=1 barrier separation);
// prologue 9 loads + VMC(3); drain VMC(6)/VMC(3)/VMC(0).
// ===========================================================================

// ---------------------------------------------------------------------------
// prep: one dispatch, region-decoded by blockIdx.x (unchanged)
// ---------------------------------------------------------------------------
__global__ __launch_bounds__(256) void prep_kernel(
    const float* __restrict__ w1, const float4* __restrict__ w2f,
    const float4* __restrict__ xf, const float* __restrict__ b1,
    const float* __restrict__ b2,
    unsigned short* __restrict__ w1t, ushort4* __restrict__ w2b,
    ushort4* __restrict__ xb, float* __restrict__ bp) {
    const int blk = blockIdx.x;
    const int t   = threadIdx.x;
    if (blk < 512) {
        __shared__ float tile[32][33];
        const int tileI = blk & 15;
        const int tileH = blk >> 4;
        const int iBase = tileI * 32, hBase = tileH * 32;
        const int col = t & 31, rowq = t >> 5;
#pragma unroll
        for (int p = 0; p < 4; ++p) {
            const int row = p * 8 + rowq;
            tile[row][col] = w1[(size_t)(hBase + row) * DIN + iBase + col];
        }
        __syncthreads();
#pragma unroll
        for (int p = 0; p < 4; ++p) {
            const int row = p * 8 + rowq;
            w1t[(size_t)(iBase + row) * DHID + hBase + col] = f2bf(tile[col][row]);
        }
    } else if (blk < 2560) {
        __shared__ float wsum[4];
        const int o = blk - 512;
        const size_t g = (size_t)o * 256 + t;
        float4 v = w2f[g];
        ushort4 ob;
        ob.x = f2bf(v.x); ob.y = f2bf(v.y); ob.z = f2bf(v.z); ob.w = f2bf(v.w);
        w2b[g] = ob;
        float4 bv = ((const float4*)b1)[t];
        float s = v.x * bv.x + v.y * bv.y + v.z * bv.z + v.w * bv.w;
#pragma unroll
        for (int off = 1; off < 64; off <<= 1) s += __shfl_xor(s, off);
        if ((t & 63) == 0) wsum[t >> 6] = s;
        __syncthreads();
        if (t == 0) bp[o] = wsum[0] + wsum[1] + wsum[2] + wsum[3] + b2[o];
    } else {
        const size_t g = (size_t)(blk - 2560) * 256 + t;
        float4 v = xf[g];
        ushort4 o;
        o.x = f2bf(v.x); o.y = f2bf(v.y); o.z = f2bf(v.z); o.w = f2bf(v.w);
        xb[g] = o;
    }
}

// ---------------------------------------------------------------------------
// gemmW: W[o,i] = sum_h w2b[o,h] * w1t[i,h]. (unchanged)
// ---------------------------------------------------------------------------
__global__ __launch_bounds__(256) void gemmW_kernel(
    const unsigned short* __restrict__ A,
    const unsigned short* __restrict__ Bw,
    unsigned short* __restrict__ W) {
    constexpr int K = DHID;
    __shared__ __align__(16) unsigned short sA[64 * 128];
    __shared__ __align__(16) unsigned short sB[64 * 128];

    const int tid  = threadIdx.x;
    const int lane = tid & 63;
    const int wid  = tid >> 6;
    const int wr = wid >> 1, wc = wid & 1;
    const int r = lane & 15, q = lane >> 4;
    const int blockN = blockIdx.x * 64;
    const int blockM = blockIdx.y * 64;

    const int chKey = (tid & 15) ^ ((tid >> 4) & 15);
    const size_t aBase = (size_t)(blockM + (tid >> 4)) * K + chKey * 8;
    const size_t bBase = (size_t)(blockN + (tid >> 4)) * K + chKey * 8;

    f32x4 acc[2][2];
#pragma unroll
    for (int mt = 0; mt < 2; ++mt)
#pragma unroll
        for (int nt = 0; nt < 2; ++nt) { f32x4 z = {0.f, 0.f, 0.f, 0.f}; acc[mt][nt] = z; }

    for (int k0 = 0; k0 < K; k0 += 128) {
#pragma unroll
        for (int j = 0; j < 4; ++j) {
            gload_lds16(A  + aBase + (size_t)j * 16 * K + k0, sA + j * 2048 + wid * 512);
            gload_lds16(Bw + bBase + (size_t)j * 16 * K + k0, sB + j * 2048 + wid * 512);
        }
        __syncthreads();
#pragma unroll
        for (int ks = 0; ks < 4; ++ks) {
            const int ch = ((ks << 2) + q) ^ r;
            bf16x8 af[2], bf[2];
#pragma unroll
            for (int mt = 0; mt < 2; ++mt) af[mt] = *(const bf16x8*)&sA[(wr * 32 + mt * 16 + r) * 128 + ch * 8];
#pragma unroll
            for (int nt = 0; nt < 2; ++nt) bf[nt] = *(const bf16x8*)&sB[(wc * 32 + nt * 16 + r) * 128 + ch * 8];
#pragma unroll
            for (int mt = 0; mt < 2; ++mt)
#pragma unroll
                for (int nt = 0; nt < 2; ++nt)
                    acc[mt][nt] = __builtin_amdgcn_mfma_f32_16x16x32_bf16(af[mt], bf[nt], acc[mt][nt], 0, 0, 0);
        }
        __syncthreads();
    }

#pragma unroll
    for (int mt = 0; mt < 2; ++mt) {
        const int row0 = blockM + wr * 32 + mt * 16 + q * 4;
#pragma unroll
        for (int nt = 0; nt < 2; ++nt) {
            const int col = blockN + wc * 32 + nt * 16 + r;
#pragma unroll
            for (int reg = 0; reg < 4; ++reg)
                W[(size_t)(row0 + reg) * DIN + col] = f2bf(acc[mt][nt][reg]);
        }
    }
}

// ---------------------------------------------------------------------------
// gemmS r18: persistent, BM=256 x BN=128, 8 waves (4M x 2N), acc[4][4].
// LDS (shorts): A units (256x32k, 8192 sh) at buf*16384 + kh*8192  [0,32768)
//               B units (128x32k, 4096 sh) at 32768 + buf*8192 + kh*4096
//               bias 1024 f32 at short-offset 49152. Total 100 KB.
// Unit layout: row-major rows x 32k, chunk c (16B) holds global chunk
// c ^ ((row>>1)&3) (pre-swizzled source, linear dest). Frag read chunk
// q ^ ((r>>1)&3) -> 2-way bank alias = free. (r15-validated geometry.)
// ---------------------------------------------------------------------------
__global__ __launch_bounds__(512, 2) void gemmS_kernel(
    const unsigned short* __restrict__ A,   // xb bf16 [BATCH, DIN]
    const unsigned short* __restrict__ Bw,  // W bf16 [DOUT, DIN]
    const float* __restrict__ bp,           // b' [DOUT]
    float* __restrict__ partials) {         // [BATCH, 4]
    constexpr int K = DIN;                   // 512 -> 8 K-tiles per N-tile
    __shared__ __align__(16) unsigned short lds[51200];  // 100 KB

    const int tid  = threadIdx.x;            // 0..511
    const int lane = tid & 63;
    const int wid  = tid >> 6;               // 0..7
    const int wr   = wid >> 1;               // 0..3 (M)
    const int wc   = wid & 1;                // 0..1 (N)
    const int r    = lane & 15, q = lane >> 4;

    // 256 blocks = 8 xcd x 32. mIdx = xcd*16 + (j>>1) (0..127), nHalf = j&1.
    // Per XCD: 32 blocks, B working set = full W (2MB) -> L2-resident.
    const int b     = blockIdx.x;
    const int xcd   = b & 7;
    const int j     = b >> 3;                // 0..31
    const int nHalf = j & 1;
    const int blockM = (xcd * 16 + (j >> 1)) * 256;
    const int nBase  = nHalf * 1024;         // walks 8 N-tiles of 128 cols

    // staging addresses (pre-swizzled global source)
    const int sRow = tid >> 2;               // 0..127 (A's j=1 adds 128)
    const int swz  = (tid & 3) ^ ((tid >> 3) & 3);
    const unsigned short* aSrc = A  + (size_t)(blockM + sRow) * K + swz * 8;
    const unsigned short* bCur = Bw + (size_t)(nBase  + sRow) * K + swz * 8;
    float* biasLds = (float*)(lds + 49152);

    // A unit: 2 gloads (rows 0-127, 128-255). B unit: 1 gload (rows 0-127).
#define STAGE_A(ptr, buf, kh, kt) do {                                          \
    gload_lds16((ptr) + (kt) * 64 + (kh) * 32,                                  \
                lds + (buf) * 16384 + (kh) * 8192 + wid * 512);                 \
    gload_lds16((ptr) + 128 * K + (kt) * 64 + (kh) * 32,                        \
                lds + (buf) * 16384 + (kh) * 8192 + 4096 + wid * 512);          \
} while (0)
#define STAGE_B(ptr, buf, kh, kt) do {                                          \
    gload_lds16((ptr) + (kt) * 64 + (kh) * 32,                                  \
                lds + 32768 + (buf) * 8192 + (kh) * 4096 + wid * 512);          \
} while (0)

    // fragment read bases (swizzled chunk)
    const int rsw  = (r >> 1) & 3;
    const int fOff = (q ^ rsw) * 8;
    const unsigned short* ldsAf = lds + (wr * 64 + r) * 32 + fOff;
    const unsigned short* ldsBf = lds + 32768 + (wc * 64 + r) * 32 + fOff;

    f32x4 acc[4][4];
#pragma unroll
    for (int mt = 0; mt < 4; ++mt)
#pragma unroll
        for (int nt = 0; nt < 4; ++nt) { f32x4 z = {0.f, 0.f, 0.f, 0.f}; acc[mt][nt] = z; }
    float mx[4][4];
#pragma unroll
    for (int mt = 0; mt < 4; ++mt)
#pragma unroll
        for (int rg = 0; rg < 4; ++rg) mx[mt][rg] = -INFINITY;
    bf16x8 af[4], bfr[4];
    float bvc[4];

#define LDA(buf, kh) do {                                                       \
    const unsigned short* p_ = ldsAf + (buf) * 16384 + (kh) * 8192;             \
    af[0] = *(const bf16x8*)(p_);                                               \
    af[1] = *(const bf16x8*)(p_ + 512);                                         \
    af[2] = *(const bf16x8*)(p_ + 1024);                                        \
    af[3] = *(const bf16x8*)(p_ + 1536);                                        \
} while (0)
#define LDB(buf, kh) do {                                                       \
    const unsigned short* p_ = ldsBf + (buf) * 8192 + (kh) * 4096;              \
    bfr[0] = *(const bf16x8*)(p_);                                              \
    bfr[1] = *(const bf16x8*)(p_ + 512);                                        \
    bfr[2] = *(const bf16x8*)(p_ + 1024);                                       \
    bfr[3] = *(const bf16x8*)(p_ + 1536);                                       \
} while (0)
#define MM() do {                                                               \
    __builtin_amdgcn_s_setprio(1);                                              \
    _Pragma("unroll") for (int m_ = 0; m_ < 4; ++m_)                            \
    _Pragma("unroll") for (int n_ = 0; n_ < 4; ++n_)                            \
        acc[m_][n_] = __builtin_amdgcn_mfma_f32_16x16x32_bf16(                  \
            af[m_], bfr[n_], acc[m_][n_], 0, 0, 0);                             \
    __builtin_amdgcn_s_setprio(0);                                              \
} while (0)
#define BAR()   __builtin_amdgcn_s_barrier()
#define LGKM0() asm volatile("s_waitcnt lgkmcnt(0)" ::: "memory")
#define VMC(n)  asm volatile("s_waitcnt vmcnt(" #n ")" ::: "memory")

    // Running-max fold (16 regs of state; no stores, no shuffles in loop).
#define FOLD() do {                                                             \
    _Pragma("unroll") for (int mt_ = 0; mt_ < 4; ++mt_)                         \
    _Pragma("unroll") for (int rg_ = 0; rg_ < 4; ++rg_) {                       \
        float v_ = fmaxf(fmaxf(acc[mt_][0][rg_] + bvc[0],                       \
                               acc[mt_][1][rg_] + bvc[1]),                      \
                         fmaxf(acc[mt_][2][rg_] + bvc[2],                       \
                               acc[mt_][3][rg_] + bvc[3]));                     \
        mx[mt_][rg_] = fmaxf(mx[mt_][rg_], v_);                                 \
    }                                                                           \
} while (0)
#define ACC_ZERO() do {                                                         \
    _Pragma("unroll") for (int mt_ = 0; mt_ < 4; ++mt_)                         \
    _Pragma("unroll") for (int nt_ = 0; nt_ < 4; ++nt_) {                       \
        f32x4 z_ = {0.f, 0.f, 0.f, 0.f}; acc[mt_][nt_] = z_;                    \
    }                                                                           \
} while (0)

    // Bias -> LDS FIRST (compiler retires its load before any STAGE issues,
    // so the counted ledger below is exact).
    {
        float2 bb = ((const float2*)(bp + nBase))[tid];
        ((float2*)biasLds)[tid] = bb;
    }
    LGKM0();

    // Prologue: t0 full (6 loads) + t1-klo (3). VMC(3) lands t0.
    STAGE_A(aSrc, 0, 0, 0); STAGE_B(bCur, 0, 0, 0);   // t0-klo
    STAGE_A(aSrc, 0, 1, 0); STAGE_B(bCur, 0, 1, 0);   // t0-khi
    STAGE_A(aSrc, 1, 0, 1); STAGE_B(bCur, 1, 0, 1);   // t1-klo
    VMC(3);
    BAR();

    // bias for N-tile 0
#pragma unroll
    for (int nt = 0; nt < 4; ++nt) bvc[nt] = biasLds[wc * 64 + nt * 16 + r];

#pragma unroll 1
    for (int ntile = 0; ntile < 8; ++ntile) {
        // 3 uniform iterations (tiles kt=2it,2it+1; stages kt 2it+1..2it+3)
#pragma unroll 1
        for (int it = 0; it < 3; ++it) {
            const int k1 = 2 * it + 1, k2 = 2 * it + 2, k3 = 2 * it + 3;
            // P1 (buf0,klo) | stage buf1-khi <- t1-khi
            LDA(0, 0); LDB(0, 0);
            STAGE_A(aSrc, 1, 1, k1); STAGE_B(bCur, 1, 1, k1); VMC(6);
            BAR(); LGKM0(); MM(); BAR();
            // P2 (buf0,khi) | stage buf0-klo <- t2-klo
            LDA(0, 1); LDB(0, 1);
            STAGE_A(aSrc, 0, 0, k2); STAGE_B(bCur, 0, 0, k2); VMC(6);
            BAR(); LGKM0(); MM(); BAR();
            // P3 (buf1,klo) | stage buf0-khi <- t2-khi
            LDA(1, 0); LDB(1, 0);
            STAGE_A(aSrc, 0, 1, k2); STAGE_B(bCur, 0, 1, k2); VMC(6);
            BAR(); LGKM0(); MM(); BAR();
            // P4 (buf1,khi) | stage buf1-klo <- t3-klo
            LDA(1, 1); LDB(1, 1);
            STAGE_A(aSrc, 1, 0, k3); STAGE_B(bCur, 1, 0, k3); VMC(6);
            BAR(); LGKM0(); MM(); BAR();
        }
        if (ntile < 7) {
            // Boundary iteration (tiles kt=6,7; stages roll into next N-tile:
            // B from bNxt, A wraps to kt=0/1).
            const unsigned short* bNxt = bCur + 128 * K;
            LDA(0, 0); LDB(0, 0);
            STAGE_A(aSrc, 1, 1, 7); STAGE_B(bCur, 1, 1, 7); VMC(6);
            BAR(); LGKM0(); MM(); BAR();
            LDA(0, 1); LDB(0, 1);
            STAGE_A(aSrc, 0, 0, 0); STAGE_B(bNxt, 0, 0, 0); VMC(6);
            BAR(); LGKM0(); MM(); BAR();
            LDA(1, 0); LDB(1, 0);
            STAGE_A(aSrc, 0, 1, 0); STAGE_B(bNxt, 0, 1, 0); VMC(6);
            BAR(); LGKM0(); MM(); BAR();
            LDA(1, 1); LDB(1, 1);
            STAGE_A(aSrc, 1, 0, 1); STAGE_B(bNxt, 1, 0, 1); VMC(6);
            BAR(); LGKM0(); MM(); BAR();
            // N-tile done: fold, zero, advance bias + B pointer.
            FOLD();
            ACC_ZERO();
#pragma unroll
            for (int nt = 0; nt < 4; ++nt)
                bvc[nt] = biasLds[(ntile + 1) * 128 + wc * 64 + nt * 16 + r];
            bCur = bNxt;
        } else {
            // Drain (tiles 62,63 in K-slot terms): only t63-khi to stage.
            LDA(0, 0); LDB(0, 0);
            STAGE_A(aSrc, 1, 1, 7); STAGE_B(bCur, 1, 1, 7); VMC(6);
            BAR(); LGKM0(); MM(); BAR();
            LDA(0, 1); LDB(0, 1); VMC(3);
            BAR(); LGKM0(); MM(); BAR();
            LDA(1, 0); LDB(1, 0); VMC(0);
            BAR(); LGKM0(); MM(); BAR();
            LDA(1, 1); LDB(1, 1);
            BAR(); LGKM0(); MM();
            FOLD();
        }
    }

#undef STAGE_A
#undef STAGE_B
#undef LDA
#undef LDB
#undef MM
#undef BAR
#undef LGKM0
#undef VMC
#undef FOLD
#undef ACC_ZERO

    // Final epilogue (once): 16-lane reduce of mx, store partials [BATCH,4].
#pragma unroll
    for (int mt = 0; mt < 4; ++mt) {
#pragma unroll
        for (int rg = 0; rg < 4; ++rg) {
            float v = mx[mt][rg];
#pragma unroll
            for (int off = 1; off < 16; off <<= 1)
                v = fmaxf(v, __shfl_xor(v, off));
            if (r == 0) {
                const int row = blockM + wr * 64 + mt * 16 + q * 4 + rg;
                partials[(size_t)row * 4 + nHalf * 2 + wc] = v;
            }
        }
    }
}

// ---------------------------------------------------------------------------
// reduce: 4 partials per row -> final max
// ---------------------------------------------------------------------------
__global__ __launch_bounds__(256) void reduce_kernel(
    const float4* __restrict__ partials, float* __restrict__ out) {
    const int row = blockIdx.x * blockDim.x + threadIdx.x;
    float4 v = partials[row];
    out[row] = fmaxf(fmaxf(v.x, v.y), fmaxf(v.z, v.w));
}

// ---------------------------------------------------------------------------
extern "C" void kernel_launch(void* const* d_in, const int* in_sizes, int n_in,
                              void* d_out, int out_size, void* d_ws, size_t ws_size,
                              hipStream_t stream) {
    const float* x   = (const float*)d_in[0];
    const float* l1w = (const float*)d_in[1];
    const float* l1b = (const float*)d_in[2];
    const float* w2  = (const float*)d_in[3];
    const float* b2  = (const float*)d_in[4];
    float* out = (float*)d_out;

    char* ws = (char*)d_ws;
    unsigned short* w1t = (unsigned short*)(ws);                 //  1 MB  w1^T bf16 [512,1024]
    unsigned short* w2b = (unsigned short*)(ws + 1048576);       //  4 MB  w2 bf16 [2048,1024]
    unsigned short* Wb  = (unsigned short*)(ws + 5242880);       //  2 MB  W bf16 [2048,512]
    float* bp           = (float*)(ws + 7340032);                //  8 KB  b' fp32 [2048]
    unsigned short* xb  = (unsigned short*)(ws + 7348224);       // 32 MB  x bf16 [32768,512]
    float* partials     = (float*)(ws + 40902656);               // 512 KB [BATCH,4]

    // 1) fused pre-work: w1 transpose + w2 cvt(+bgemv) + x cvt
    prep_kernel<<<18944, 256, 0, stream>>>(
        l1w, (const float4*)w2, (const float4*)x, l1b, b2,
        w1t, (ushort4*)w2b, (ushort4*)xb, bp);

    // 2) W = w2b @ w1t^T  [2048, 512]
    gemmW_kernel<<<dim3(DIN / 64, DOUT / 64), 256, 0, stream>>>(w2b, w1t, Wb);

    // 3) scores = xb @ W^T + b', fused row-max (persistent, 256 blocks)
    gemmS_kernel<<<256, 512, 0, stream>>>(xb, Wb, bp, partials);

    // 4) final max over 4 partials per row
    reduce_kernel<<<BATCH / 256, 256, 0, stream>>>((const float4*)partials, out);
}

// Round 5
// 183.159 us; speedup vs baseline: 2.0893x; 1.0232x over previous
//
#include <hip/hip_runtime.h>
#include <hip/hip_bf16.h>
#include <stdint.h>

// Problem sizes (compile-time)
static constexpr int BATCH = 32768;
static constexpr int DIN   = 512;
static constexpr int DHID  = 1024;
static constexpr int DOUT  = 2048;

typedef __bf16 bf16x8 __attribute__((ext_vector_type(8)));
typedef float  f32x4  __attribute__((ext_vector_type(4)));

// fp32 -> bf16 round-to-nearest-even
__device__ __forceinline__ unsigned short f2bf(float f) {
    unsigned int u = __float_as_uint(f);
    u += 0x7FFFu + ((u >> 16) & 1u);
    return (unsigned short)(u >> 16);
}

// async global->LDS, 16B per lane. LDS dest = WAVE-uniform base + 16*(lane&63).
__device__ __forceinline__ void gload_lds16(const void* g, void* l) {
    __builtin_amdgcn_global_load_lds((__attribute__((address_space(1))) void*)g,
                                     (__attribute__((address_space(3))) void*)l,
                                     16, 0, 0);
}

// ===========================================================================
// scores = x @ W^T + b' (algebraic fusion; absmax 0.03125 measured)
// r19 = r18 minus the MID-PHASE barrier. r18's cycle model (measured):
// phase = 1395 cyc = 620 (128 MFMA/CU) + 770 (64KB ds_read_b128 @85B/cyc),
// serially summed because BAR between the read burst and the MFMA burst
// lockstepped all 8 waves. Single end-of-phase barrier keeps every hazard:
//   WAR: each stage target was last read ONE phase earlier; those reads
//        finish at that phase's lgkm0, all waves pass its END-bar before
//        the overwriting stage issues.
//   RAW: slot staged at p is VMC-forced at p+2 (before p+2's end-bar),
//        published by that bar, read at p+3. Unchanged ledger.
//   own-wave: compiler lgkmcnt + explicit LGKM0.
// Waves now slip within a phase -> read burst hides under MFMA burst.
// ===========================================================================

// ---------------------------------------------------------------------------
// prep: one dispatch, region-decoded by blockIdx.x (unchanged)
// ---------------------------------------------------------------------------
__global__ __launch_bounds__(256) void prep_kernel(
    const float* __restrict__ w1, const float4* __restrict__ w2f,
    const float4* __restrict__ xf, const float* __restrict__ b1,
    const float* __restrict__ b2,
    unsigned short* __restrict__ w1t, ushort4* __restrict__ w2b,
    ushort4* __restrict__ xb, float* __restrict__ bp) {
    const int blk = blockIdx.x;
    const int t   = threadIdx.x;
    if (blk < 512) {
        __shared__ float tile[32][33];
        const int tileI = blk & 15;
        const int tileH = blk >> 4;
        const int iBase = tileI * 32, hBase = tileH * 32;
        const int col = t & 31, rowq = t >> 5;
#pragma unroll
        for (int p = 0; p < 4; ++p) {
            const int row = p * 8 + rowq;
            tile[row][col] = w1[(size_t)(hBase + row) * DIN + iBase + col];
        }
        __syncthreads();
#pragma unroll
        for (int p = 0; p < 4; ++p) {
            const int row = p * 8 + rowq;
            w1t[(size_t)(iBase + row) * DHID + hBase + col] = f2bf(tile[col][row]);
        }
    } else if (blk < 2560) {
        __shared__ float wsum[4];
        const int o = blk - 512;
        const size_t g = (size_t)o * 256 + t;
        float4 v = w2f[g];
        ushort4 ob;
        ob.x = f2bf(v.x); ob.y = f2bf(v.y); ob.z = f2bf(v.z); ob.w = f2bf(v.w);
        w2b[g] = ob;
        float4 bv = ((const float4*)b1)[t];
        float s = v.x * bv.x + v.y * bv.y + v.z * bv.z + v.w * bv.w;
#pragma unroll
        for (int off = 1; off < 64; off <<= 1) s += __shfl_xor(s, off);
        if ((t & 63) == 0) wsum[t >> 6] = s;
        __syncthreads();
        if (t == 0) bp[o] = wsum[0] + wsum[1] + wsum[2] + wsum[3] + b2[o];
    } else {
        const size_t g = (size_t)(blk - 2560) * 256 + t;
        float4 v = xf[g];
        ushort4 o;
        o.x = f2bf(v.x); o.y = f2bf(v.y); o.z = f2bf(v.z); o.w = f2bf(v.w);
        xb[g] = o;
    }
}

// ---------------------------------------------------------------------------
// gemmW: W[o,i] = sum_h w2b[o,h] * w1t[i,h]. (unchanged)
// ---------------------------------------------------------------------------
__global__ __launch_bounds__(256) void gemmW_kernel(
    const unsigned short* __restrict__ A,
    const unsigned short* __restrict__ Bw,
    unsigned short* __restrict__ W) {
    constexpr int K = DHID;
    __shared__ __align__(16) unsigned short sA[64 * 128];
    __shared__ __align__(16) unsigned short sB[64 * 128];

    const int tid  = threadIdx.x;
    const int lane = tid & 63;
    const int wid  = tid >> 6;
    const int wr = wid >> 1, wc = wid & 1;
    const int r = lane & 15, q = lane >> 4;
    const int blockN = blockIdx.x * 64;
    const int blockM = blockIdx.y * 64;

    const int chKey = (tid & 15) ^ ((tid >> 4) & 15);
    const size_t aBase = (size_t)(blockM + (tid >> 4)) * K + chKey * 8;
    const size_t bBase = (size_t)(blockN + (tid >> 4)) * K + chKey * 8;

    f32x4 acc[2][2];
#pragma unroll
    for (int mt = 0; mt < 2; ++mt)
#pragma unroll
        for (int nt = 0; nt < 2; ++nt) { f32x4 z = {0.f, 0.f, 0.f, 0.f}; acc[mt][nt] = z; }

    for (int k0 = 0; k0 < K; k0 += 128) {
#pragma unroll
        for (int j = 0; j < 4; ++j) {
            gload_lds16(A  + aBase + (size_t)j * 16 * K + k0, sA + j * 2048 + wid * 512);
            gload_lds16(Bw + bBase + (size_t)j * 16 * K + k0, sB + j * 2048 + wid * 512);
        }
        __syncthreads();
#pragma unroll
        for (int ks = 0; ks < 4; ++ks) {
            const int ch = ((ks << 2) + q) ^ r;
            bf16x8 af[2], bf[2];
#pragma unroll
            for (int mt = 0; mt < 2; ++mt) af[mt] = *(const bf16x8*)&sA[(wr * 32 + mt * 16 + r) * 128 + ch * 8];
#pragma unroll
            for (int nt = 0; nt < 2; ++nt) bf[nt] = *(const bf16x8*)&sB[(wc * 32 + nt * 16 + r) * 128 + ch * 8];
#pragma unroll
            for (int mt = 0; mt < 2; ++mt)
#pragma unroll
                for (int nt = 0; nt < 2; ++nt)
                    acc[mt][nt] = __builtin_amdgcn_mfma_f32_16x16x32_bf16(af[mt], bf[nt], acc[mt][nt], 0, 0, 0);
        }
        __syncthreads();
    }

#pragma unroll
    for (int mt = 0; mt < 2; ++mt) {
        const int row0 = blockM + wr * 32 + mt * 16 + q * 4;
#pragma unroll
        for (int nt = 0; nt < 2; ++nt) {
            const int col = blockN + wc * 32 + nt * 16 + r;
#pragma unroll
            for (int reg = 0; reg < 4; ++reg)
                W[(size_t)(row0 + reg) * DIN + col] = f2bf(acc[mt][nt][reg]);
        }
    }
}

// ---------------------------------------------------------------------------
// gemmS r19: persistent, BM=256 x BN=128, 8 waves (4M x 2N), acc[4][4].
// Single barrier per phase (end-of-phase). Otherwise identical to r18:
// LDS (shorts): A units at buf*16384 + kh*8192 [0,32768); B units at
// 32768 + buf*8192 + kh*4096; bias 1024 f32 at short-offset 49152. 100 KB.
// Unit: rows x 32k, chunk c holds global chunk c ^ ((row>>1)&3)
// (pre-swizzled source, linear dest); frag read chunk q ^ ((r>>1)&3).
// ---------------------------------------------------------------------------
__global__ __launch_bounds__(512, 2) void gemmS_kernel(
    const unsigned short* __restrict__ A,   // xb bf16 [BATCH, DIN]
    const unsigned short* __restrict__ Bw,  // W bf16 [DOUT, DIN]
    const float* __restrict__ bp,           // b' [DOUT]
    float* __restrict__ partials) {         // [BATCH, 4]
    constexpr int K = DIN;                   // 512 -> 8 K-tiles per N-tile
    __shared__ __align__(16) unsigned short lds[51200];  // 100 KB

    const int tid  = threadIdx.x;            // 0..511
    const int lane = tid & 63;
    const int wid  = tid >> 6;               // 0..7
    const int wr   = wid >> 1;               // 0..3 (M)
    const int wc   = wid & 1;                // 0..1 (N)
    const int r    = lane & 15, q = lane >> 4;

    // 256 blocks = 8 xcd x 32. mIdx = xcd*16 + (j>>1) (0..127), nHalf = j&1.
    const int b     = blockIdx.x;
    const int xcd   = b & 7;
    const int j     = b >> 3;                // 0..31
    const int nHalf = j & 1;
    const int blockM = (xcd * 16 + (j >> 1)) * 256;
    const int nBase  = nHalf * 1024;         // walks 8 N-tiles of 128 cols

    // staging addresses (pre-swizzled global source)
    const int sRow = tid >> 2;               // 0..127 (A's j=1 adds 128)
    const int swz  = (tid & 3) ^ ((tid >> 3) & 3);
    const unsigned short* aSrc = A  + (size_t)(blockM + sRow) * K + swz * 8;
    const unsigned short* bCur = Bw + (size_t)(nBase  + sRow) * K + swz * 8;
    float* biasLds = (float*)(lds + 49152);

    // A unit: 2 gloads (rows 0-127, 128-255). B unit: 1 gload (rows 0-127).
#define STAGE_A(ptr, buf, kh, kt) do {                                          \
    gload_lds16((ptr) + (kt) * 64 + (kh) * 32,                                  \
                lds + (buf) * 16384 + (kh) * 8192 + wid * 512);                 \
    gload_lds16((ptr) + 128 * K + (kt) * 64 + (kh) * 32,                        \
                lds + (buf) * 16384 + (kh) * 8192 + 4096 + wid * 512);          \
} while (0)
#define STAGE_B(ptr, buf, kh, kt) do {                                          \
    gload_lds16((ptr) + (kt) * 64 + (kh) * 32,                                  \
                lds + 32768 + (buf) * 8192 + (kh) * 4096 + wid * 512);          \
} while (0)

    // fragment read bases (swizzled chunk)
    const int rsw  = (r >> 1) & 3;
    const int fOff = (q ^ rsw) * 8;
    const unsigned short* ldsAf = lds + (wr * 64 + r) * 32 + fOff;
    const unsigned short* ldsBf = lds + 32768 + (wc * 64 + r) * 32 + fOff;

    f32x4 acc[4][4];
#pragma unroll
    for (int mt = 0; mt < 4; ++mt)
#pragma unroll
        for (int nt = 0; nt < 4; ++nt) { f32x4 z = {0.f, 0.f, 0.f, 0.f}; acc[mt][nt] = z; }
    float mx[4][4];
#pragma unroll
    for (int mt = 0; mt < 4; ++mt)
#pragma unroll
        for (int rg = 0; rg < 4; ++rg) mx[mt][rg] = -INFINITY;
    bf16x8 af[4], bfr[4];
    float bvc[4];

#define LDA(buf, kh) do {                                                       \
    const unsigned short* p_ = ldsAf + (buf) * 16384 + (kh) * 8192;             \
    af[0] = *(const bf16x8*)(p_);                                               \
    af[1] = *(const bf16x8*)(p_ + 512);                                         \
    af[2] = *(const bf16x8*)(p_ + 1024);                                        \
    af[3] = *(const bf16x8*)(p_ + 1536);                                        \
} while (0)
#define LDB(buf, kh) do {                                                       \
    const unsigned short* p_ = ldsBf + (buf) * 8192 + (kh) * 4096;              \
    bfr[0] = *(const bf16x8*)(p_);                                              \
    bfr[1] = *(const bf16x8*)(p_ + 512);                                        \
    bfr[2] = *(const bf16x8*)(p_ + 1024);                                       \
    bfr[3] = *(const bf16x8*)(p_ + 1536);                                       \
} while (0)
#define MM() do {                                                               \
    __builtin_amdgcn_s_setprio(1);                                              \
    _Pragma("unroll") for (int m_ = 0; m_ < 4; ++m_)                            \
    _Pragma("unroll") for (int n_ = 0; n_ < 4; ++n_)                            \
        acc[m_][n_] = __builtin_amdgcn_mfma_f32_16x16x32_bf16(                  \
            af[m_], bfr[n_], acc[m_][n_], 0, 0, 0);                             \
    __builtin_amdgcn_s_setprio(0);                                              \
} while (0)
#define BAR()   __builtin_amdgcn_s_barrier()
#define LGKM0() asm volatile("s_waitcnt lgkmcnt(0)" ::: "memory")
#define VMC(n)  asm volatile("s_waitcnt vmcnt(" #n ")" ::: "memory")

    // Running-max fold (16 regs of state; no stores, no shuffles in loop).
#define FOLD() do {                                                             \
    _Pragma("unroll") for (int mt_ = 0; mt_ < 4; ++mt_)                         \
    _Pragma("unroll") for (int rg_ = 0; rg_ < 4; ++rg_) {                       \
        float v_ = fmaxf(fmaxf(acc[mt_][0][rg_] + bvc[0],                       \
                               acc[mt_][1][rg_] + bvc[1]),                      \
                         fmaxf(acc[mt_][2][rg_] + bvc[2],                       \
                               acc[mt_][3][rg_] + bvc[3]));                     \
        mx[mt_][rg_] = fmaxf(mx[mt_][rg_], v_);                                 \
    }                                                                           \
} while (0)
#define ACC_ZERO() do {                                                         \
    _Pragma("unroll") for (int mt_ = 0; mt_ < 4; ++mt_)                         \
    _Pragma("unroll") for (int nt_ = 0; nt_ < 4; ++nt_) {                       \
        f32x4 z_ = {0.f, 0.f, 0.f, 0.f}; acc[mt_][nt_] = z_;                    \
    }                                                                           \
} while (0)

    // Bias -> LDS FIRST (its load retires before any STAGE issues, keeping
    // the counted ledger exact).
    {
        float2 bb = ((const float2*)(bp + nBase))[tid];
        ((float2*)biasLds)[tid] = bb;
    }
    LGKM0();

    // Prologue: t0 full (6 loads) + t1-klo (3). VMC(3) lands t0.
    STAGE_A(aSrc, 0, 0, 0); STAGE_B(bCur, 0, 0, 0);   // t0-klo
    STAGE_A(aSrc, 0, 1, 0); STAGE_B(bCur, 0, 1, 0);   // t0-khi
    STAGE_A(aSrc, 1, 0, 1); STAGE_B(bCur, 1, 0, 1);   // t1-klo
    VMC(3);
    BAR();

    // bias for N-tile 0
#pragma unroll
    for (int nt = 0; nt < 4; ++nt) bvc[nt] = biasLds[wc * 64 + nt * 16 + r];

#pragma unroll 1
    for (int ntile = 0; ntile < 8; ++ntile) {
        // 3 uniform iterations (tiles kt=2it,2it+1; stages kt 2it+1..2it+3)
#pragma unroll 1
        for (int it = 0; it < 3; ++it) {
            const int k1 = 2 * it + 1, k2 = 2 * it + 2, k3 = 2 * it + 3;
            // P1 (buf0,klo) | stage buf1-khi <- t1-khi
            LDA(0, 0); LDB(0, 0);
            STAGE_A(aSrc, 1, 1, k1); STAGE_B(bCur, 1, 1, k1); VMC(6);
            LGKM0(); MM(); BAR();
            // P2 (buf0,khi) | stage buf0-klo <- t2-klo
            LDA(0, 1); LDB(0, 1);
            STAGE_A(aSrc, 0, 0, k2); STAGE_B(bCur, 0, 0, k2); VMC(6);
            LGKM0(); MM(); BAR();
            // P3 (buf1,klo) | stage buf0-khi <- t2-khi
            LDA(1, 0); LDB(1, 0);
            STAGE_A(aSrc, 0, 1, k2); STAGE_B(bCur, 0, 1, k2); VMC(6);
            LGKM0(); MM(); BAR();
            // P4 (buf1,khi) | stage buf1-klo <- t3-klo
            LDA(1, 1); LDB(1, 1);
            STAGE_A(aSrc, 1, 0, k3); STAGE_B(bCur, 1, 0, k3); VMC(6);
            LGKM0(); MM(); BAR();
        }
        if (ntile < 7) {
            // Boundary iteration (tiles kt=6,7; stages roll into next N-tile:
            // B from bNxt, A wraps to kt=0/1).
            const unsigned short* bNxt = bCur + 128 * K;
            LDA(0, 0); LDB(0, 0);
            STAGE_A(aSrc, 1, 1, 7); STAGE_B(bCur, 1, 1, 7); VMC(6);
            LGKM0(); MM(); BAR();
            LDA(0, 1); LDB(0, 1);
            STAGE_A(aSrc, 0, 0, 0); STAGE_B(bNxt, 0, 0, 0); VMC(6);
            LGKM0(); MM(); BAR();
            LDA(1, 0); LDB(1, 0);
            STAGE_A(aSrc, 0, 1, 0); STAGE_B(bNxt, 0, 1, 0); VMC(6);
            LGKM0(); MM(); BAR();
            LDA(1, 1); LDB(1, 1);
            STAGE_A(aSrc, 1, 0, 1); STAGE_B(bNxt, 1, 0, 1); VMC(6);
            LGKM0(); MM(); BAR();
            // N-tile done: fold, zero, advance bias + B pointer.
            FOLD();
            ACC_ZERO();
#pragma unroll
            for (int nt = 0; nt < 4; ++nt)
                bvc[nt] = biasLds[(ntile + 1) * 128 + wc * 64 + nt * 16 + r];
            bCur = bNxt;
        } else {
            // Drain (last 4 phases): only t63-khi to stage.
            LDA(0, 0); LDB(0, 0);
            STAGE_A(aSrc, 1, 1, 7); STAGE_B(bCur, 1, 1, 7); VMC(6);
            LGKM0(); MM(); BAR();
            LDA(0, 1); LDB(0, 1); VMC(3);
            LGKM0(); MM(); BAR();
            LDA(1, 0); LDB(1, 0); VMC(0);
            LGKM0(); MM(); BAR();
            LDA(1, 1); LDB(1, 1);
            LGKM0(); MM();
            FOLD();
        }
    }

#undef STAGE_A
#undef STAGE_B
#undef LDA
#undef LDB
#undef MM
#undef BAR
#undef LGKM0
#undef VMC
#undef FOLD
#undef ACC_ZERO

    // Final epilogue (once): 16-lane reduce of mx, store partials [BATCH,4].
#pragma unroll
    for (int mt = 0; mt < 4; ++mt) {
#pragma unroll
        for (int rg = 0; rg < 4; ++rg) {
            float v = mx[mt][rg];
#pragma unroll
            for (int off = 1; off < 16; off <<= 1)
                v = fmaxf(v, __shfl_xor(v, off));
            if (r == 0) {
                const int row = blockM + wr * 64 + mt * 16 + q * 4 + rg;
                partials[(size_t)row * 4 + nHalf * 2 + wc] = v;
            }
        }
    }
}

// ---------------------------------------------------------------------------
// reduce: 4 partials per row -> final max
// ---------------------------------------------------------------------------
__global__ __launch_bounds__(256) void reduce_kernel(
    const float4* __restrict__ partials, float* __restrict__ out) {
    const int row = blockIdx.x * blockDim.x + threadIdx.x;
    float4 v = partials[row];
    out[row] = fmaxf(fmaxf(v.x, v.y), fmaxf(v.z, v.w));
}

// ---------------------------------------------------------------------------
extern "C" void kernel_launch(void* const* d_in, const int* in_sizes, int n_in,
                              void* d_out, int out_size, void* d_ws, size_t ws_size,
                              hipStream_t stream) {
    const float* x   = (const float*)d_in[0];
    const float* l1w = (const float*)d_in[1];
    const float* l1b = (const float*)d_in[2];
    const float* w2  = (const float*)d_in[3];
    const float* b2  = (const float*)d_in[4];
    float* out = (float*)d_out;

    char* ws = (char*)d_ws;
    unsigned short* w1t = (unsigned short*)(ws);                 //  1 MB  w1^T bf16 [512,1024]
    unsigned short* w2b = (unsigned short*)(ws + 1048576);       //  4 MB  w2 bf16 [2048,1024]
    unsigned short* Wb  = (unsigned short*)(ws + 5242880);       //  2 MB  W bf16 [2048,512]
    float* bp           = (float*)(ws + 7340032);                //  8 KB  b' fp32 [2048]
    unsigned short* xb  = (unsigned short*)(ws + 7348224);       // 32 MB  x bf16 [32768,512]
    float* partials     = (float*)(ws + 40902656);               // 512 KB [BATCH,4]

    // 1) fused pre-work: w1 transpose + w2 cvt(+bgemv) + x cvt
    prep_kernel<<<18944, 256, 0, stream>>>(
        l1w, (const float4*)w2, (const float4*)x, l1b, b2,
        w1t, (ushort4*)w2b, (ushort4*)xb, bp);

    // 2) W = w2b @ w1t^T  [2048, 512]
    gemmW_kernel<<<dim3(DIN / 64, DOUT / 64), 256, 0, stream>>>(w2b, w1t, Wb);

    // 3) scores = xb @ W^T + b', fused row-max (persistent, 256 blocks)
    gemmS_kernel<<<256, 512, 0, stream>>>(xb, Wb, bp, partials);

    // 4) final max over 4 partials per row
    reduce_kernel<<<BATCH / 256, 256, 0, stream>>>((const float4*)partials, out);
}